// Round 15
// baseline (4048.737 us; speedup 1.0000x reference)
//
#include <hip/hip_runtime.h>
#include <math.h>

// LSTM: I=5, H=64, L=3, O=1, B=1024, T=256, fp32 in/out.
// Round-18: 2 blocks/CU TLP (TBr=2, NB=512) on the r15 lockstep base.
// r17 POST-MORTEM: spin-poll flags regressed (203->344us): spinning waves
// steal SIMD issue from producers; volatile LDS polling serializes lgkmcnt.
// Sync-structure scan complete: lockstep-1-barrier(203) < stagger(236) <
// spin(344). Intra-block scheduling CANNOT hide the ~960cy barrier+chain
// stall. THIS ROUND: hide it with TLP across INDEPENDENT blocks: TBr=2,
// NB=512 -> 2 workgroups/CU; they barrier independently, so block B issues
// MFMAs while block A drains its barrier/combine chain. No protocol.
// Resources: VGPR 76(r15)x6 waves/SIMD=456<=512; LDS 2x17.4KB=35KB<=160.
// __launch_bounds__(768,6) pins cap 85 to guarantee co-residency (r15=76,
// margin 9; if this forces spill -> r5 FETCH signature -> revert).
// TBr=2 mechanics: real batch b at tile row 4b, b in {0,1} = kg<2 lanes;
// combine computed by all lanes (trans issue is exec-masked anyway), WRITES
// guarded kg<TBr; rows 8,12 stay zero; lreal tightened to cols {0,4} (dead
// A-rows read nothing; persistent zero frags = LDS zeros, bit-identical).
// MFMA padding waste doubles but matrix pipe was 42% idle -> rides free.
// Kept from r15 (best known): single lgkmcnt-only barrier per step, native
// __expf, cvt_pk publish, exec-masked frag loads, hi-only h (RNE) + fp32
// h2f sidecar, row-scatter combine=1j, bias as C-operand, rcp-merged i*g
// (safe: |preact|<=~12), fused imm-offset LDS + loop-invariant pointers
// (incl kg*16 k-slice), 2x parity unroll, persistent frags, setprio.
// Layouts (r8 hw-verified): C/D col=lane&15,row=(lane>>4)*4+reg;
// A row=lane&15, k=(lane>>4)*8+j.

typedef __attribute__((ext_vector_type(8))) short bf16x8;
typedef __attribute__((ext_vector_type(4))) float f32x4;

constexpr int Hh  = 64;
constexpr int Tt  = 256;
constexpr int In  = 5;
constexpr int TBr = 2;     // REAL batch rows per block (tile rows 0,4)
constexpr int NB  = 512;   // blocks (NB*TBr = 1024 = B); 2 blocks/CU
constexpr int NT  = 768;   // threads (12 waves)

// LDS geometry (bytes), hi-only: one array, immediate-offset addressable.
constexpr int RB_ = 144;    // row stride (72 shorts, bank-spread pad)
constexpr int LB  = 2304;   // layer stride (16 rows * 144)
constexpr int PB  = 8192;   // parity stride (6912 used, padded to pow2)

__device__ __forceinline__ float tanhc(float x) {
    // tanh(x) = 2*sigmoid(2x) - 1; saturates correctly, NaN-free
    return fmaf(2.0f, __builtin_amdgcn_rcpf(1.0f + __expf(-2.0f * x)), -1.0f);
}

// fp32 -> bf16 round-to-nearest-even (weight load path only, not hot)
__device__ __forceinline__ short f2bf_rne(float f) {
    union { float f; unsigned u; } v; v.f = f;
    unsigned r = (v.u + 0x7fffu + ((v.u >> 16) & 1u)) >> 16;
    return (short)r;
}
// fp32 -> (hi,lo) bf16 pair via truncation; hi+lo ~= f to ~2^-16 rel (x only)
__device__ __forceinline__ void split_bf(float f, short& hi, short& lo) {
    union { float f; unsigned u; } v; v.f = f;
    hi = (short)(v.u >> 16);
    union { unsigned u; float f; } h; h.u = v.u & 0xffff0000u;
    float r = f - h.f;
    union { float f; unsigned u; } w; w.f = r;
    lo = (short)(w.u >> 16);
}

__device__ __forceinline__ bf16x8 ldwfrag(const float* __restrict__ W,
                                          int n, int stride, int k0, int kmax) {
    bf16x8 r;
    #pragma unroll
    for (int j = 0; j < 8; ++j) {
        int k = k0 + j;
        float f = (k < kmax) ? W[n * stride + k] : 0.0f;
        r[j] = f2bf_rne(f);
    }
    return r;
}

#define MF(A, B, C) __builtin_amdgcn_mfma_f32_16x16x32_bf16(A, B, C, 0, 0, 0)

// Barrier: drain LDS ops only (writes visible), skip vmcnt (x load stays in
// flight; compiler waits vmcnt at the use point).
#define LBAR() asm volatile("s_waitcnt lgkmcnt(0)\n\ts_barrier" ::: "memory")

// One pipelined timestep. RO: own-layer read base (this iter's read parity),
// RBp: below-layer read base, WR: write base (opposite parity).
#define STEP(TI, RO, RBp, WR) do {                                           \
    const int ti_ = (TI);                                                    \
    const bool act_ = (wg == 0) ? (ti_ < Tt)                                 \
                    : (wg == 1) ? (ti_ >= 1 && ti_ <= Tt)                    \
                                : (ti_ >= 2);                                \
    if (act_) {                                                              \
        if (xmask) {   /* split prefetched x(t) into frags */                \
            _Pragma("unroll")                                                \
            for (int jj = 0; jj < In; ++jj) {                                \
                short h_, l_; split_bf(xr[jj], h_, l_);                      \
                xhi[jj] = h_; xlo[jj] = l_;                                  \
            }                                                                \
        }                                                                    \
        if (lreal) {   /* exec-masked frag loads: real rows only */          \
            oh0 = *(const bf16x8*)(RO);                                      \
            oh1 = *(const bf16x8*)((RO) + 64);                               \
            if (wg > 0) {                                                    \
                bh0 = *(const bf16x8*)(RBp);                                 \
                bh1 = *(const bf16x8*)((RBp) + 64);                          \
            }                                                                \
        }                                                                    \
        f32x4 acc[4];                                                        \
        __builtin_amdgcn_s_setprio(1);                                       \
        _Pragma("unroll")                                                    \
        for (int gi = 0; gi < 4; ++gi)                                       \
            acc[gi] = MF(oh0, WH[gi][0], bsv[gi]);   /* bias as C */         \
        _Pragma("unroll")                                                    \
        for (int gi = 0; gi < 4; ++gi)                                       \
            acc[gi] = MF(oh1, WH[gi][1], acc[gi]);                           \
        if (wg == 0) {                     /* input: x(t), hi+lo */          \
            _Pragma("unroll")                                                \
            for (int gi = 0; gi < 4; ++gi)                                   \
                acc[gi] = MF(xhi, WI[gi][0], acc[gi]);                       \
            _Pragma("unroll")                                                \
            for (int gi = 0; gi < 4; ++gi)                                   \
                acc[gi] = MF(xlo, WI[gi][0], acc[gi]);                       \
        } else {                           /* input: h_below(t), hi-only */  \
            _Pragma("unroll")                                                \
            for (int gi = 0; gi < 4; ++gi)                                   \
                acc[gi] = MF(bh0, WI[gi][0], acc[gi]);                       \
            _Pragma("unroll")                                                \
            for (int gi = 0; gi < 4; ++gi)                                   \
                acc[gi] = MF(bh1, WI[gi][1], acc[gi]);                       \
        }                                                                    \
        __builtin_amdgcn_s_setprio(0);                                       \
        if (xmask && ti_ + 1 < Tt) {       /* prefetch x(t+1) */             \
            _Pragma("unroll")                                                \
            for (int jj = 0; jj < In; ++jj)                                  \
                xr[jj] = x[xbase + (size_t)(ti_ + 1) * In + jj];             \
        }                                                                    \
        /* combine, j=0: (b=kg, u=ub+col); real only for kg<TBr */           \
        float ei = __expf(-acc[0][0]);                                       \
        float ef = __expf(-acc[1][0]);                                       \
        float eg = __expf(-2.0f * acc[2][0]);                                \
        float eo = __expf(-acc[3][0]);                                       \
        float ig = (1.0f - eg) *                                             \
                   __builtin_amdgcn_rcpf((1.0f + ei) * (1.0f + eg));         \
        float fv = __builtin_amdgcn_rcpf(1.0f + ef);                         \
        float cn = fmaf(fv, c0, ig);                                         \
        c0 = cn;                                                             \
        float ov = __builtin_amdgcn_rcpf(1.0f + eo);                         \
        float hn = ov * tanhc(cn);                                           \
        unsigned pk_;                                                        \
        asm("v_cvt_pk_bf16_f32 %0, %1, %2" : "=v"(pk_) : "v"(hn), "v"(hn));  \
        if (kg < TBr) {                    /* write guard: real rows only */ \
            *(short*)(WR) = (short)pk_;                                      \
            if (wg == 2) h2f[kg][ub + col] = hn;   /* fp32 sidecar */        \
        }                                                                    \
    }                                                                        \
    LBAR();                                                                  \
} while (0)

__global__ __launch_bounds__(NT, 6) void lstm3_mfma(
    const float* __restrict__ x,
    const float* __restrict__ w_ih0, const float* __restrict__ w_hh0,
    const float* __restrict__ b_ih0, const float* __restrict__ b_hh0,
    const float* __restrict__ w_ih1, const float* __restrict__ w_hh1,
    const float* __restrict__ b_ih1, const float* __restrict__ b_hh1,
    const float* __restrict__ w_ih2, const float* __restrict__ w_hh2,
    const float* __restrict__ b_ih2, const float* __restrict__ b_hh2,
    const float* __restrict__ w_fc,  const float* __restrict__ b_fc,
    float* __restrict__ out)
{
    // [parity PB | layer LB | row RB_] fused hi-only h buffer (16 KB)
    __shared__ short hb[2][PB / 2];
    __shared__ float h2f[TBr][Hh];      // fp32 h2 sidecar

    const int tid = threadIdx.x;
    const int l   = tid & 63;
    const int wid = tid >> 6;        // 0..11
    const int wg  = wid >> 2;        // layer group 0..2
    const int w4  = wid & 3;         // wave within layer
    const int ub  = w4 * 16;         // unit base
    const int col = l & 15;          // A-row / B-col index
    const int kg  = l >> 4;          // k-group 0..3
    const int b0  = blockIdx.x * TBr;
    // lane's A-row is a real batch row: col in {0,4} (rows 4b, b<TBr)
    const bool lreal = ((col & 3) == 0) && ((col >> 2) < TBr);

    // ---- zero both parities (pipeline fill; dead rows stay 0) ----
    for (int i = tid; i < PB * 2 / 4; i += NT) ((int*)hb)[i] = 0;

    // ---- per-layer weight selection ----
    const float* whh = (wg == 0) ? w_hh0 : (wg == 1) ? w_hh1 : w_hh2;
    const float* wih = (wg == 0) ? w_ih0 : (wg == 1) ? w_ih1 : w_ih2;
    const float* bih = (wg == 0) ? b_ih0 : (wg == 1) ? b_ih1 : b_ih2;
    const float* bhh = (wg == 0) ? b_hh0 : (wg == 1) ? b_hh1 : b_hh2;

    // ---- weights -> register fragments (once); bias pre-splat as C ----
    bf16x8 WH[4][2], WI[4][2];
    f32x4  bsv[4];
    #pragma unroll
    for (int gi = 0; gi < 4; ++gi) {
        int n = gi * 64 + ub + col;
        float bs_ = bih[n] + bhh[n];
        bsv[gi] = (f32x4){bs_, bs_, bs_, bs_};
        #pragma unroll
        for (int kt = 0; kt < 2; ++kt) {
            WH[gi][kt] = ldwfrag(whh, n, Hh, kt * 32 + kg * 8, Hh);
            if (wg == 0) {
                WI[gi][kt] = (kt == 0) ? ldwfrag(wih, n, In, kg * 8, In)
                                       : ldwfrag(wih, n, In, 64, 0);
            } else {
                WI[gi][kt] = ldwfrag(wih, n, Hh, kt * 32 + kg * 8, Hh);
            }
        }
    }

    // ---- loop-invariant LDS base pointers (read incl. kg*16 k-slice!) ----
    char* hbB = (char*)hb;
    const int lbelow = (wg > 0) ? (wg - 1) : 0;
    const int lown   = (wg > 0) ? LB : 0;       // own = below + LB (wg0: +0)
    const char* rbB_ = hbB + lbelow * LB + col * RB_ + kg * 16;   // parity 0
    const char* rbA_ = rbB_ + PB;                                 // parity 1
    const char* roA  = rbA_ + lown;
    const char* roB  = rbB_ + lown;
    // write: real batch b=kg lives at tile row 4*kg (j=0 slot of kg)
    char* wrA = hbB + wg * LB + (kg * 4) * RB_ + (ub + col) * 2;  // parity 0
    char* wrB = wrA + PB;                                         // parity 1

    // ---- x prefetch: only lanes whose A-row is real ----
    const bool xmask = (wg == 0) && (kg == 0) && lreal;
    const size_t xbase = (size_t)(b0 + (col >> 2)) * Tt * In;
    float xr[5] = {0.f, 0.f, 0.f, 0.f, 0.f};
    // persistent fragments: dead lanes keep zeros forever (= LDS zeros)
    bf16x8 xhi, xlo, oh0, oh1, bh0, bh1;
    #pragma unroll
    for (int j = 0; j < 8; ++j) {
        xhi[j] = 0; xlo[j] = 0; oh0[j] = 0; oh1[j] = 0; bh0[j] = 0; bh1[j] = 0;
    }
    if (xmask) {
        #pragma unroll
        for (int j = 0; j < In; ++j) xr[j] = x[xbase + j];
    }

    float c0 = 0.f;   // cell state for (b=kg, u=ub+col); kg>=TBr: garbage, unused

    __syncthreads();

    // ---- systolic main loop: 258 iterations, manually 2x unrolled ----
    #pragma unroll 1
    for (int t2 = 0; t2 < Tt + 2; t2 += 2) {
        STEP(t2,     roA, rbA_, wrA);   // reads parity 1, writes parity 0
        STEP(t2 + 1, roB, rbB_, wrB);   // reads parity 0, writes parity 1
    }

    // ---- final FC on h2(T-1) from the fp32 sidecar ----
    if (tid < TBr) {
        const int b = tid;
        float accf = b_fc[0];
        #pragma unroll 1
        for (int u = 0; u < Hh; ++u)
            accf = fmaf(h2f[b][u], w_fc[u], accf);
        out[b0 + b] = accf;
    }
}

extern "C" void kernel_launch(void* const* d_in, const int* in_sizes, int n_in,
                              void* d_out, int out_size, void* d_ws, size_t ws_size,
                              hipStream_t stream) {
    const float* x     = (const float*)d_in[0];
    const float* w_ih0 = (const float*)d_in[1];
    const float* w_hh0 = (const float*)d_in[2];
    const float* b_ih0 = (const float*)d_in[3];
    const float* b_hh0 = (const float*)d_in[4];
    const float* w_ih1 = (const float*)d_in[5];
    const float* w_hh1 = (const float*)d_in[6];
    const float* b_ih1 = (const float*)d_in[7];
    const float* b_hh1 = (const float*)d_in[8];
    const float* w_ih2 = (const float*)d_in[9];
    const float* w_hh2 = (const float*)d_in[10];
    const float* b_ih2 = (const float*)d_in[11];
    const float* b_hh2 = (const float*)d_in[12];
    const float* w_fc  = (const float*)d_in[13];
    const float* b_fc  = (const float*)d_in[14];
    float* out = (float*)d_out;

    lstm3_mfma<<<NB, NT, 0, stream>>>(x,
        w_ih0, w_hh0, b_ih0, b_hh0,
        w_ih1, w_hh1, b_ih1, b_hh1,
        w_ih2, w_hh2, b_ih2, b_hh2,
        w_fc, b_fc, out);
}

// Round 16
// 447.720 us; speedup vs baseline: 9.0430x; 9.0430x over previous
//
#include <hip/hip_runtime.h>
#include <math.h>

// LSTM: I=5, H=64, L=3, O=1, B=1024, T=256, fp32 in/out.
// Round-19: r18's TLP experiment, correctly run (launch_bounds back to 2).
// r18 POST-MORTEM: __launch_bounds__(768,6) capped VGPR at 85 -> allocator
// collapsed to 40 VGPR + spilled the 64-reg weight set (FETCH 3.9MB->13GB,
// r5 signature). The TLP hypothesis never executed. Arithmetic: per-SIMD
// VGPR pool 512 (m69); r15's 76 VGPR -> floor(512/76)=6 waves/SIMD = 24
// waves/CU = TWO 12-wave blocks co-reside NATURALLY. LDS 2x16.9KB=34KB ok.
// r15 ran 1 block/CU only because NB=256 supplies one block per CU.
// THIS ROUND: NB=512/TBr=2 with __launch_bounds__(768,2) (advisory, no
// cap). Independent blocks interleave: block B's MFMAs fill block A's
// barrier/combine stall (~950cy of the 1890cy pace). Ceiling becomes MFMA
// pipe saturation. DIAGNOSTIC TREE: VGPR<=85 & Occ~67% & dur~140-190 =
// win; VGPR>85 -> Occ 34%, dur ~400 -> shed regs next (x hi-only);
// Occ 67% but dur ~200 -> shared-pipe saturated, r15 is the floor.
// TBr=2 mechanics (from r18): real batch b at tile rows {0,4} (b=kg<2);
// writes guarded kg<TBr; lreal = col in {0,4}; rows 8,12 stay zero.
// Kept from r15: single lgkmcnt-only barrier/step, native __expf, cvt_pk
// publish, exec-masked frag loads, hi-only h (RNE) + fp32 h2f sidecar,
// row-scatter combine=1j, bias as C-operand, rcp-merged i*g (safe:
// |preact|<=~12), fused imm-offset LDS + loop-invariant pointers (incl
// kg*16 k-slice), 2x parity unroll, persistent frags, setprio.
// Layouts (r8 hw-verified): C/D col=lane&15,row=(lane>>4)*4+reg;
// A row=lane&15, k=(lane>>4)*8+j.
// DO NOT set launch_bounds min-waves > 2 (r5, r18: allocator spills).

typedef __attribute__((ext_vector_type(8))) short bf16x8;
typedef __attribute__((ext_vector_type(4))) float f32x4;

constexpr int Hh  = 64;
constexpr int Tt  = 256;
constexpr int In  = 5;
constexpr int TBr = 2;     // REAL batch rows per block (tile rows 0,4)
constexpr int NB  = 512;   // blocks (NB*TBr = 1024 = B); 2 blocks/CU
constexpr int NT  = 768;   // threads (12 waves)

// LDS geometry (bytes), hi-only: one array, immediate-offset addressable.
constexpr int RB_ = 144;    // row stride (72 shorts, bank-spread pad)
constexpr int LB  = 2304;   // layer stride (16 rows * 144)
constexpr int PB  = 8192;   // parity stride (6912 used, padded to pow2)

__device__ __forceinline__ float tanhc(float x) {
    // tanh(x) = 2*sigmoid(2x) - 1; saturates correctly, NaN-free
    return fmaf(2.0f, __builtin_amdgcn_rcpf(1.0f + __expf(-2.0f * x)), -1.0f);
}

// fp32 -> bf16 round-to-nearest-even (weight load path only, not hot)
__device__ __forceinline__ short f2bf_rne(float f) {
    union { float f; unsigned u; } v; v.f = f;
    unsigned r = (v.u + 0x7fffu + ((v.u >> 16) & 1u)) >> 16;
    return (short)r;
}
// fp32 -> (hi,lo) bf16 pair via truncation; hi+lo ~= f to ~2^-16 rel (x only)
__device__ __forceinline__ void split_bf(float f, short& hi, short& lo) {
    union { float f; unsigned u; } v; v.f = f;
    hi = (short)(v.u >> 16);
    union { unsigned u; float f; } h; h.u = v.u & 0xffff0000u;
    float r = f - h.f;
    union { float f; unsigned u; } w; w.f = r;
    lo = (short)(w.u >> 16);
}

__device__ __forceinline__ bf16x8 ldwfrag(const float* __restrict__ W,
                                          int n, int stride, int k0, int kmax) {
    bf16x8 r;
    #pragma unroll
    for (int j = 0; j < 8; ++j) {
        int k = k0 + j;
        float f = (k < kmax) ? W[n * stride + k] : 0.0f;
        r[j] = f2bf_rne(f);
    }
    return r;
}

#define MF(A, B, C) __builtin_amdgcn_mfma_f32_16x16x32_bf16(A, B, C, 0, 0, 0)

// Barrier: drain LDS ops only (writes visible), skip vmcnt (x load stays in
// flight; compiler waits vmcnt at the use point).
#define LBAR() asm volatile("s_waitcnt lgkmcnt(0)\n\ts_barrier" ::: "memory")

// One pipelined timestep. RO: own-layer read base (this iter's read parity),
// RBp: below-layer read base, WR: write base (opposite parity).
#define STEP(TI, RO, RBp, WR) do {                                           \
    const int ti_ = (TI);                                                    \
    const bool act_ = (wg == 0) ? (ti_ < Tt)                                 \
                    : (wg == 1) ? (ti_ >= 1 && ti_ <= Tt)                    \
                                : (ti_ >= 2);                                \
    if (act_) {                                                              \
        if (xmask) {   /* split prefetched x(t) into frags */                \
            _Pragma("unroll")                                                \
            for (int jj = 0; jj < In; ++jj) {                                \
                short h_, l_; split_bf(xr[jj], h_, l_);                      \
                xhi[jj] = h_; xlo[jj] = l_;                                  \
            }                                                                \
        }                                                                    \
        if (lreal) {   /* exec-masked frag loads: real rows only */          \
            oh0 = *(const bf16x8*)(RO);                                      \
            oh1 = *(const bf16x8*)((RO) + 64);                               \
            if (wg > 0) {                                                    \
                bh0 = *(const bf16x8*)(RBp);                                 \
                bh1 = *(const bf16x8*)((RBp) + 64);                          \
            }                                                                \
        }                                                                    \
        f32x4 acc[4];                                                        \
        __builtin_amdgcn_s_setprio(1);                                       \
        _Pragma("unroll")                                                    \
        for (int gi = 0; gi < 4; ++gi)                                       \
            acc[gi] = MF(oh0, WH[gi][0], bsv[gi]);   /* bias as C */         \
        _Pragma("unroll")                                                    \
        for (int gi = 0; gi < 4; ++gi)                                       \
            acc[gi] = MF(oh1, WH[gi][1], acc[gi]);                           \
        if (wg == 0) {                     /* input: x(t), hi+lo */          \
            _Pragma("unroll")                                                \
            for (int gi = 0; gi < 4; ++gi)                                   \
                acc[gi] = MF(xhi, WI[gi][0], acc[gi]);                       \
            _Pragma("unroll")                                                \
            for (int gi = 0; gi < 4; ++gi)                                   \
                acc[gi] = MF(xlo, WI[gi][0], acc[gi]);                       \
        } else {                           /* input: h_below(t), hi-only */  \
            _Pragma("unroll")                                                \
            for (int gi = 0; gi < 4; ++gi)                                   \
                acc[gi] = MF(bh0, WI[gi][0], acc[gi]);                       \
            _Pragma("unroll")                                                \
            for (int gi = 0; gi < 4; ++gi)                                   \
                acc[gi] = MF(bh1, WI[gi][1], acc[gi]);                       \
        }                                                                    \
        __builtin_amdgcn_s_setprio(0);                                       \
        if (xmask && ti_ + 1 < Tt) {       /* prefetch x(t+1) */             \
            _Pragma("unroll")                                                \
            for (int jj = 0; jj < In; ++jj)                                  \
                xr[jj] = x[xbase + (size_t)(ti_ + 1) * In + jj];             \
        }                                                                    \
        /* combine, j=0: (b=kg, u=ub+col); real only for kg<TBr */           \
        float ei = __expf(-acc[0][0]);                                       \
        float ef = __expf(-acc[1][0]);                                       \
        float eg = __expf(-2.0f * acc[2][0]);                                \
        float eo = __expf(-acc[3][0]);                                       \
        float ig = (1.0f - eg) *                                             \
                   __builtin_amdgcn_rcpf((1.0f + ei) * (1.0f + eg));         \
        float fv = __builtin_amdgcn_rcpf(1.0f + ef);                         \
        float cn = fmaf(fv, c0, ig);                                         \
        c0 = cn;                                                             \
        float ov = __builtin_amdgcn_rcpf(1.0f + eo);                         \
        float hn = ov * tanhc(cn);                                           \
        unsigned pk_;                                                        \
        asm("v_cvt_pk_bf16_f32 %0, %1, %2" : "=v"(pk_) : "v"(hn), "v"(hn));  \
        if (kg < TBr) {                    /* write guard: real rows only */ \
            *(short*)(WR) = (short)pk_;                                      \
            if (wg == 2) h2f[kg][ub + col] = hn;   /* fp32 sidecar */        \
        }                                                                    \
    }                                                                        \
    LBAR();                                                                  \
} while (0)

__global__ __launch_bounds__(NT, 2) void lstm3_mfma(
    const float* __restrict__ x,
    const float* __restrict__ w_ih0, const float* __restrict__ w_hh0,
    const float* __restrict__ b_ih0, const float* __restrict__ b_hh0,
    const float* __restrict__ w_ih1, const float* __restrict__ w_hh1,
    const float* __restrict__ b_ih1, const float* __restrict__ b_hh1,
    const float* __restrict__ w_ih2, const float* __restrict__ w_hh2,
    const float* __restrict__ b_ih2, const float* __restrict__ b_hh2,
    const float* __restrict__ w_fc,  const float* __restrict__ b_fc,
    float* __restrict__ out)
{
    // [parity PB | layer LB | row RB_] fused hi-only h buffer (16 KB)
    __shared__ short hb[2][PB / 2];
    __shared__ float h2f[TBr][Hh];      // fp32 h2 sidecar

    const int tid = threadIdx.x;
    const int l   = tid & 63;
    const int wid = tid >> 6;        // 0..11
    const int wg  = wid >> 2;        // layer group 0..2
    const int w4  = wid & 3;         // wave within layer
    const int ub  = w4 * 16;         // unit base
    const int col = l & 15;          // A-row / B-col index
    const int kg  = l >> 4;          // k-group 0..3
    const int b0  = blockIdx.x * TBr;
    // lane's A-row is a real batch row: col in {0,4} (rows 4b, b<TBr)
    const bool lreal = ((col & 3) == 0) && ((col >> 2) < TBr);

    // ---- zero both parities (pipeline fill; dead rows stay 0) ----
    for (int i = tid; i < PB * 2 / 4; i += NT) ((int*)hb)[i] = 0;

    // ---- per-layer weight selection ----
    const float* whh = (wg == 0) ? w_hh0 : (wg == 1) ? w_hh1 : w_hh2;
    const float* wih = (wg == 0) ? w_ih0 : (wg == 1) ? w_ih1 : w_ih2;
    const float* bih = (wg == 0) ? b_ih0 : (wg == 1) ? b_ih1 : b_ih2;
    const float* bhh = (wg == 0) ? b_hh0 : (wg == 1) ? b_hh1 : b_hh2;

    // ---- weights -> register fragments (once); bias pre-splat as C ----
    bf16x8 WH[4][2], WI[4][2];
    f32x4  bsv[4];
    #pragma unroll
    for (int gi = 0; gi < 4; ++gi) {
        int n = gi * 64 + ub + col;
        float bs_ = bih[n] + bhh[n];
        bsv[gi] = (f32x4){bs_, bs_, bs_, bs_};
        #pragma unroll
        for (int kt = 0; kt < 2; ++kt) {
            WH[gi][kt] = ldwfrag(whh, n, Hh, kt * 32 + kg * 8, Hh);
            if (wg == 0) {
                WI[gi][kt] = (kt == 0) ? ldwfrag(wih, n, In, kg * 8, In)
                                       : ldwfrag(wih, n, In, 64, 0);
            } else {
                WI[gi][kt] = ldwfrag(wih, n, Hh, kt * 32 + kg * 8, Hh);
            }
        }
    }

    // ---- loop-invariant LDS base pointers (read incl. kg*16 k-slice!) ----
    char* hbB = (char*)hb;
    const int lbelow = (wg > 0) ? (wg - 1) : 0;
    const int lown   = (wg > 0) ? LB : 0;       // own = below + LB (wg0: +0)
    const char* rbB_ = hbB + lbelow * LB + col * RB_ + kg * 16;   // parity 0
    const char* rbA_ = rbB_ + PB;                                 // parity 1
    const char* roA  = rbA_ + lown;
    const char* roB  = rbB_ + lown;
    // write: real batch b=kg lives at tile row 4*kg (j=0 slot of kg)
    char* wrA = hbB + wg * LB + (kg * 4) * RB_ + (ub + col) * 2;  // parity 0
    char* wrB = wrA + PB;                                         // parity 1

    // ---- x prefetch: only lanes whose A-row is real ----
    const bool xmask = (wg == 0) && (kg == 0) && lreal;
    const size_t xbase = (size_t)(b0 + (col >> 2)) * Tt * In;
    float xr[5] = {0.f, 0.f, 0.f, 0.f, 0.f};
    // persistent fragments: dead lanes keep zeros forever (= LDS zeros)
    bf16x8 xhi, xlo, oh0, oh1, bh0, bh1;
    #pragma unroll
    for (int j = 0; j < 8; ++j) {
        xhi[j] = 0; xlo[j] = 0; oh0[j] = 0; oh1[j] = 0; bh0[j] = 0; bh1[j] = 0;
    }
    if (xmask) {
        #pragma unroll
        for (int j = 0; j < In; ++j) xr[j] = x[xbase + j];
    }

    float c0 = 0.f;   // cell state for (b=kg, u=ub+col); kg>=TBr: unused

    __syncthreads();

    // ---- systolic main loop: 258 iterations, manually 2x unrolled ----
    #pragma unroll 1
    for (int t2 = 0; t2 < Tt + 2; t2 += 2) {
        STEP(t2,     roA, rbA_, wrA);   // reads parity 1, writes parity 0
        STEP(t2 + 1, roB, rbB_, wrB);   // reads parity 0, writes parity 1
    }

    // ---- final FC on h2(T-1) from the fp32 sidecar ----
    if (tid < TBr) {
        const int b = tid;
        float accf = b_fc[0];
        #pragma unroll 1
        for (int u = 0; u < Hh; ++u)
            accf = fmaf(h2f[b][u], w_fc[u], accf);
        out[b0 + b] = accf;
    }
}

extern "C" void kernel_launch(void* const* d_in, const int* in_sizes, int n_in,
                              void* d_out, int out_size, void* d_ws, size_t ws_size,
                              hipStream_t stream) {
    const float* x     = (const float*)d_in[0];
    const float* w_ih0 = (const float*)d_in[1];
    const float* w_hh0 = (const float*)d_in[2];
    const float* b_ih0 = (const float*)d_in[3];
    const float* b_hh0 = (const float*)d_in[4];
    const float* w_ih1 = (const float*)d_in[5];
    const float* w_hh1 = (const float*)d_in[6];
    const float* b_ih1 = (const float*)d_in[7];
    const float* b_hh1 = (const float*)d_in[8];
    const float* w_ih2 = (const float*)d_in[9];
    const float* w_hh2 = (const float*)d_in[10];
    const float* b_ih2 = (const float*)d_in[11];
    const float* b_hh2 = (const float*)d_in[12];
    const float* w_fc  = (const float*)d_in[13];
    const float* b_fc  = (const float*)d_in[14];
    float* out = (float*)d_out;

    lstm3_mfma<<<NB, NT, 0, stream>>>(x,
        w_ih0, w_hh0, b_ih0, b_hh0,
        w_ih1, w_hh1, b_ih1, b_hh1,
        w_ih2, w_hh2, b_ih2, b_hh2,
        w_fc, b_fc, out);
}

// Round 17
// 252.090 us; speedup vs baseline: 16.0607x; 1.7760x over previous
//
#include <hip/hip_runtime.h>
#include <math.h>

// LSTM: I=5, H=64, L=3, O=1, B=1024, T=256, fp32 in/out.
// Round-20: r15 base (TBr=4, NB=256 restored) + three issue micro-cuts.
// r19 POST-MORTEM: VGPR=76, Occ stayed 35%, dur=2x r15 -> two 12-wave
// blocks CANNOT co-reside: m69 VGPR quantum (waves/CU halves at 64/128)
// caps 16 waves/CU for 65-128 VGPR. <=64 combined is impossible (weights
// alone = 64 regs; +16 acc). TLP-via-co-residency is structurally DEAD for
// weights-in-registers; weights-in-LDS costs ~2300cy/step ds_reads (worse
// than the ~950cy stall it hides). Sync scan: lockstep(203) < stagger(236)
// < spin(344) < sequential-2x(405). r15 structure is the floor; remaining
// lever = issue count.
// THIS ROUND: 1) remove s_setprio (m190: hurts lockstep barrier-synced
// structures); 2) split x(t+1) right after its load (post-MFMA region) so
// the pre-MFMA critical head starts at the frag loads; 3) x HI-ONLY
// (accuracy bet #2): -4 MFMA/wg0-wave/step, halved split. Predicted
// absmax 3-6e-4 vs 9.5e-4 (input-path noise 1.8e-4 rms, gate-damped).
// If absmax fails -> revert to x hi+lo, keep the rest.
// Kept from r15: single lgkmcnt-only barrier/step, native __expf, cvt_pk
// publish, exec-masked frag loads, hi-only h (RNE) + fp32 h2f sidecar,
// row-scatter combine=1j (all 64 lanes real at TBr=4), bias as C-operand,
// rcp-merged i*g (safe: |preact|<=~12), fused imm-offset LDS +
// loop-invariant pointers (incl kg*16 k-slice), 2x parity unroll,
// persistent frags.
// Layouts (r8 hw-verified): C/D col=lane&15,row=(lane>>4)*4+reg;
// A row=lane&15, k=(lane>>4)*8+j.
// DO NOT set launch_bounds min-waves > 2 (r5, r18: allocator spills).

typedef __attribute__((ext_vector_type(8))) short bf16x8;
typedef __attribute__((ext_vector_type(4))) float f32x4;

constexpr int Hh  = 64;
constexpr int Tt  = 256;
constexpr int In  = 5;
constexpr int TBr = 4;     // REAL batch rows per block (tile rows 0,4,8,12)
constexpr int NB  = 256;   // blocks (NB*TBr = 1024 = B); 1 block/CU
constexpr int NT  = 768;   // threads (12 waves)

// LDS geometry (bytes), hi-only: one array, immediate-offset addressable.
constexpr int RB_ = 144;    // row stride (72 shorts, bank-spread pad)
constexpr int LB  = 2304;   // layer stride (16 rows * 144)
constexpr int PB  = 8192;   // parity stride (6912 used, padded to pow2)

__device__ __forceinline__ float tanhc(float x) {
    // tanh(x) = 2*sigmoid(2x) - 1; saturates correctly, NaN-free
    return fmaf(2.0f, __builtin_amdgcn_rcpf(1.0f + __expf(-2.0f * x)), -1.0f);
}

// fp32 -> bf16 round-to-nearest-even (weight/x load path)
__device__ __forceinline__ short f2bf_rne(float f) {
    union { float f; unsigned u; } v; v.f = f;
    unsigned r = (v.u + 0x7fffu + ((v.u >> 16) & 1u)) >> 16;
    return (short)r;
}

__device__ __forceinline__ bf16x8 ldwfrag(const float* __restrict__ W,
                                          int n, int stride, int k0, int kmax) {
    bf16x8 r;
    #pragma unroll
    for (int j = 0; j < 8; ++j) {
        int k = k0 + j;
        float f = (k < kmax) ? W[n * stride + k] : 0.0f;
        r[j] = f2bf_rne(f);
    }
    return r;
}

#define MF(A, B, C) __builtin_amdgcn_mfma_f32_16x16x32_bf16(A, B, C, 0, 0, 0)

// Barrier: drain LDS ops only (writes visible), skip vmcnt (x load stays in
// flight; compiler waits vmcnt at the use point).
#define LBAR() asm volatile("s_waitcnt lgkmcnt(0)\n\ts_barrier" ::: "memory")

// One pipelined timestep. RO: own-layer read base (this iter's read parity),
// RBp: below-layer read base, WR: write base (opposite parity).
#define STEP(TI, RO, RBp, WR) do {                                           \
    const int ti_ = (TI);                                                    \
    const bool act_ = (wg == 0) ? (ti_ < Tt)                                 \
                    : (wg == 1) ? (ti_ >= 1 && ti_ <= Tt)                    \
                                : (ti_ >= 2);                                \
    if (act_) {                                                              \
        if (lreal) {   /* exec-masked frag loads: real rows only */          \
            oh0 = *(const bf16x8*)(RO);                                      \
            oh1 = *(const bf16x8*)((RO) + 64);                               \
            if (wg > 0) {                                                    \
                bh0 = *(const bf16x8*)(RBp);                                 \
                bh1 = *(const bf16x8*)((RBp) + 64);                          \
            }                                                                \
        }                                                                    \
        f32x4 acc[4];                                                        \
        _Pragma("unroll")                                                    \
        for (int gi = 0; gi < 4; ++gi)                                       \
            acc[gi] = MF(oh0, WH[gi][0], bsv[gi]);   /* bias as C */         \
        _Pragma("unroll")                                                    \
        for (int gi = 0; gi < 4; ++gi)                                       \
            acc[gi] = MF(oh1, WH[gi][1], acc[gi]);                           \
        if (wg == 0) {                     /* input: x(t), HI-ONLY */        \
            _Pragma("unroll")                                                \
            for (int gi = 0; gi < 4; ++gi)                                   \
                acc[gi] = MF(xhi, WI[gi][0], acc[gi]);                       \
        } else {                           /* input: h_below(t), hi-only */  \
            _Pragma("unroll")                                                \
            for (int gi = 0; gi < 4; ++gi)                                   \
                acc[gi] = MF(bh0, WI[gi][0], acc[gi]);                       \
            _Pragma("unroll")                                                \
            for (int gi = 0; gi < 4; ++gi)                                   \
                acc[gi] = MF(bh1, WI[gi][1], acc[gi]);                       \
        }                                                                    \
        if (xmask && ti_ + 1 < Tt) {  /* load + split x(t+1) OFF the head */ \
            _Pragma("unroll")                                                \
            for (int jj = 0; jj < In; ++jj)                                  \
                xr[jj] = x[xbase + (size_t)(ti_ + 1) * In + jj];             \
            _Pragma("unroll")                                                \
            for (int jj = 0; jj < In; ++jj)                                  \
                xhi[jj] = f2bf_rne(xr[jj]);                                  \
        }                                                                    \
        /* combine, j=0 only: output (b=kg, u=ub+col), all 64 lanes real */  \
        float ei = __expf(-acc[0][0]);                                       \
        float ef = __expf(-acc[1][0]);                                       \
        float eg = __expf(-2.0f * acc[2][0]);                                \
        float eo = __expf(-acc[3][0]);                                       \
        float ig = (1.0f - eg) *                                             \
                   __builtin_amdgcn_rcpf((1.0f + ei) * (1.0f + eg));         \
        float fv = __builtin_amdgcn_rcpf(1.0f + ef);                         \
        float cn = fmaf(fv, c0, ig);                                         \
        c0 = cn;                                                             \
        float ov = __builtin_amdgcn_rcpf(1.0f + eo);                         \
        float hn = ov * tanhc(cn);                                           \
        unsigned pk_;                                                        \
        asm("v_cvt_pk_bf16_f32 %0, %1, %2" : "=v"(pk_) : "v"(hn), "v"(hn));  \
        *(short*)(WR) = (short)pk_;                                          \
        if (wg == 2) h2f[kg][ub + col] = hn;   /* fp32 sidecar for FC */     \
    }                                                                        \
    LBAR();                                                                  \
} while (0)

__global__ __launch_bounds__(NT, 2) void lstm3_mfma(
    const float* __restrict__ x,
    const float* __restrict__ w_ih0, const float* __restrict__ w_hh0,
    const float* __restrict__ b_ih0, const float* __restrict__ b_hh0,
    const float* __restrict__ w_ih1, const float* __restrict__ w_hh1,
    const float* __restrict__ b_ih1, const float* __restrict__ b_hh1,
    const float* __restrict__ w_ih2, const float* __restrict__ w_hh2,
    const float* __restrict__ b_ih2, const float* __restrict__ b_hh2,
    const float* __restrict__ w_fc,  const float* __restrict__ b_fc,
    float* __restrict__ out)
{
    // [parity PB | layer LB | row RB_] fused hi-only h buffer (16 KB)
    __shared__ short hb[2][PB / 2];
    __shared__ float h2f[TBr][Hh];      // fp32 h2 sidecar (1 KB)

    const int tid = threadIdx.x;
    const int l   = tid & 63;
    const int wid = tid >> 6;        // 0..11
    const int wg  = wid >> 2;        // layer group 0..2
    const int w4  = wid & 3;         // wave within layer
    const int ub  = w4 * 16;         // unit base
    const int col = l & 15;          // A-row / B-col index
    const int kg  = l >> 4;          // k-group 0..3
    const int b0  = blockIdx.x * TBr;
    const bool lreal = ((col & 3) == 0);   // lane's A-row is a real batch row

    // ---- zero both parities (pipeline fill; dead rows stay 0) ----
    for (int i = tid; i < PB * 2 / 4; i += NT) ((int*)hb)[i] = 0;

    // ---- per-layer weight selection ----
    const float* whh = (wg == 0) ? w_hh0 : (wg == 1) ? w_hh1 : w_hh2;
    const float* wih = (wg == 0) ? w_ih0 : (wg == 1) ? w_ih1 : w_ih2;
    const float* bih = (wg == 0) ? b_ih0 : (wg == 1) ? b_ih1 : b_ih2;
    const float* bhh = (wg == 0) ? b_hh0 : (wg == 1) ? b_hh1 : b_hh2;

    // ---- weights -> register fragments (once); bias pre-splat as C ----
    bf16x8 WH[4][2], WI[4][2];
    f32x4  bsv[4];
    #pragma unroll
    for (int gi = 0; gi < 4; ++gi) {
        int n = gi * 64 + ub + col;
        float bs_ = bih[n] + bhh[n];
        bsv[gi] = (f32x4){bs_, bs_, bs_, bs_};
        #pragma unroll
        for (int kt = 0; kt < 2; ++kt) {
            WH[gi][kt] = ldwfrag(whh, n, Hh, kt * 32 + kg * 8, Hh);
            if (wg == 0) {
                WI[gi][kt] = (kt == 0) ? ldwfrag(wih, n, In, kg * 8, In)
                                       : ldwfrag(wih, n, In, 64, 0);
            } else {
                WI[gi][kt] = ldwfrag(wih, n, Hh, kt * 32 + kg * 8, Hh);
            }
        }
    }

    // ---- loop-invariant LDS base pointers (read incl. kg*16 k-slice!) ----
    char* hbB = (char*)hb;
    const int lbelow = (wg > 0) ? (wg - 1) : 0;
    const int lown   = (wg > 0) ? LB : 0;       // own = below + LB (wg0: +0)
    const char* rbB_ = hbB + lbelow * LB + col * RB_ + kg * 16;   // parity 0
    const char* rbA_ = rbB_ + PB;                                 // parity 1
    const char* roA  = rbA_ + lown;
    const char* roB  = rbB_ + lown;
    // write: real batch b=kg lives at tile row 4*kg (j=0 slot of kg)
    char* wrA = hbB + wg * LB + (kg * 4) * RB_ + (ub + col) * 2;  // parity 0
    char* wrB = wrA + PB;                                         // parity 1

    // ---- x prefetch: only lanes whose A-row is real (col%4==0) ----
    const bool xmask = (wg == 0) && (kg == 0) && lreal;
    const size_t xbase = (size_t)(b0 + (col >> 2)) * Tt * In;
    float xr[5] = {0.f, 0.f, 0.f, 0.f, 0.f};
    // persistent fragments: dead lanes keep zeros forever (= LDS zeros)
    bf16x8 xhi, oh0, oh1, bh0, bh1;
    #pragma unroll
    for (int j = 0; j < 8; ++j) {
        xhi[j] = 0; oh0[j] = 0; oh1[j] = 0; bh0[j] = 0; bh1[j] = 0;
    }
    if (xmask) {   // load + split x(0) before the loop
        #pragma unroll
        for (int j = 0; j < In; ++j) xr[j] = x[xbase + j];
        #pragma unroll
        for (int j = 0; j < In; ++j) xhi[j] = f2bf_rne(xr[j]);
    }

    float c0 = 0.f;   // cell state for (b=kg, u=ub+col)

    __syncthreads();

    // ---- systolic main loop: 258 iterations, manually 2x unrolled ----
    #pragma unroll 1
    for (int t2 = 0; t2 < Tt + 2; t2 += 2) {
        STEP(t2,     roA, rbA_, wrA);   // reads parity 1, writes parity 0
        STEP(t2 + 1, roB, rbB_, wrB);   // reads parity 0, writes parity 1
    }

    // ---- final FC on h2(T-1) from the fp32 sidecar ----
    if (tid < TBr) {
        const int b = tid;
        float accf = b_fc[0];
        #pragma unroll 1
        for (int u = 0; u < Hh; ++u)
            accf = fmaf(h2f[b][u], w_fc[u], accf);
        out[b0 + b] = accf;
    }
}

extern "C" void kernel_launch(void* const* d_in, const int* in_sizes, int n_in,
                              void* d_out, int out_size, void* d_ws, size_t ws_size,
                              hipStream_t stream) {
    const float* x     = (const float*)d_in[0];
    const float* w_ih0 = (const float*)d_in[1];
    const float* w_hh0 = (const float*)d_in[2];
    const float* b_ih0 = (const float*)d_in[3];
    const float* b_hh0 = (const float*)d_in[4];
    const float* w_ih1 = (const float*)d_in[5];
    const float* w_hh1 = (const float*)d_in[6];
    const float* b_ih1 = (const float*)d_in[7];
    const float* b_hh1 = (const float*)d_in[8];
    const float* w_ih2 = (const float*)d_in[9];
    const float* w_hh2 = (const float*)d_in[10];
    const float* b_ih2 = (const float*)d_in[11];
    const float* b_hh2 = (const float*)d_in[12];
    const float* w_fc  = (const float*)d_in[13];
    const float* b_fc  = (const float*)d_in[14];
    float* out = (float*)d_out;

    lstm3_mfma<<<NB, NT, 0, stream>>>(x,
        w_ih0, w_hh0, b_ih0, b_hh0,
        w_ih1, w_hh1, b_ih1, b_hh1,
        w_ih2, w_hh2, b_ih2, b_hh2,
        w_fc, b_fc, out);
}